// Round 16
// baseline (188.617 us; speedup 1.0000x reference)
//
#include <hip/hip_runtime.h>
#include <hip/hip_bf16.h>

typedef unsigned int u32;
typedef unsigned short u16;

using bf16x8 = __attribute__((ext_vector_type(8))) short;
using f32x4  = __attribute__((ext_vector_type(4))) float;

// ---------------- workspace layout (bytes), total 409088 ----------------
#define OFF_IN    0L        // [128][72] str144 (k0..62)            18432
#define OFF_SKIP  18432L    // [128][72] str144                      18432
#define OFF_VIEW  36864L    // [128][40] str80  (k0..26)             10240
#define HOFF(i)   (47104L + (long)(i) * 32768L)
// heavy i: chunk0 [128][64] str128 XOR-swz (k0..63) 16384 ; chunk1 same @+16384
// heavy order: 0=Wc 1..4=Wb0..3 5=Wskipc 6..9=Wb4..7 10=Wviewc
#define OFF_B0S   407552L   // f32[128] b_in+b_c
#define OFF_BSK   408064L   // f32[128] b_skip+b_skipc
#define OFF_BV    408576L   // f32[128] b_view+b_viewc

// ---------------- LDS layout (bytes): 37888 -> 4 blocks/CU ----------------
#define LDS_X   0        // activations/cond [64][136] bf16 stride 272 = 17408
#define LDS_W   17408    // weight buffer (18432 max: IN/SKIP str144; heavies 16384)
#define LDS_SP  35840    // sigma partials [64][2] f32 = 512
#define LDS_RP  36352    // rgb partials [64][2][3] f32 = 1536
#define LDS_TOTAL 37888  // x4 blocks = 151552 <= 163840

__device__ __forceinline__ u16 f2bf(float x) {
  union { float f; u32 u; } un; un.f = x;
  u32 u = un.u;
  return (u16)((u + 0x7fffu + ((u >> 16) & 1u)) >> 16);
}
__device__ __forceinline__ u32 pack2(float a, float b) {
  u32 r;
  asm("v_cvt_pk_bf16_f32 %0, %1, %2" : "=v"(r) : "v"(a), "v"(b));
  return r;
}
__device__ __forceinline__ float sel3(float a, float b, float c, int i) {
  return i == 0 ? a : (i == 1 ? b : c);
}
__device__ __forceinline__ float enc_val3(float a, float b, float c, int e, int kreal) {
  if (e >= kreal) return 0.f;
  if (e < 3) return sel3(a, b, c, e);
  int t = e - 3;
  int l = t / 6;
  int rem = t - l * 6;
  int pi = rem >= 3 ? rem - 3 : rem;
  float x = sel3(a, b, c, pi) * (float)(1 << l);
  return rem < 3 ? __sinf(x) : __cosf(x);
}
__device__ __forceinline__ bf16x8 mk8(u32 a, u32 b, u32 c, u32 d) {
  union { u32 u[4]; bf16x8 v; } t; t.u[0] = a; t.u[1] = b; t.u[2] = c; t.u[3] = d;
  return t.v;
}
__device__ __forceinline__ void gll16(const void* g, void* l) {
  __builtin_amdgcn_global_load_lds(
      (const __attribute__((address_space(1))) void*)g,
      (__attribute__((address_space(3))) void*)l, 16, 0, 0);
}
#define MFMA __builtin_amdgcn_mfma_f32_16x16x32_bf16
#define PRIO(n) __builtin_amdgcn_s_setprio(n)

// ---------------- prep: weights (R13 layout) + combined biases ----------------
__global__ void prep_kernel(
    const float* __restrict__ Win, const float* __restrict__ Wc, const float* __restrict__ Wb,
    const float* __restrict__ Wskip, const float* __restrict__ Wskipc,
    const float* __restrict__ Wview, const float* __restrict__ Wviewc,
    const float* __restrict__ bin, const float* __restrict__ bc,
    const float* __restrict__ bskip, const float* __restrict__ bskipc,
    const float* __restrict__ bview, const float* __restrict__ bviewc,
    char* __restrict__ ws) {
  int i = blockIdx.x * 256 + threadIdx.x;
  if (i >= 204160) return;
  int r = i;
  const float* src;
  if (r < 9216)                  { src = Win;
    int n = r / 72, c = r % 72;
    float v = (c < 63) ? src[(long)c * 128 + n] : 0.f;
    *(u16*)(ws + OFF_IN + ((long)n * 72 + c) * 2) = f2bf(v); return; }
  else if ((r -= 9216) < 9216)   { src = Wskip;
    int n = r / 72, c = r % 72;
    float v = (c < 63) ? src[(long)c * 128 + n] : 0.f;
    *(u16*)(ws + OFF_SKIP + ((long)n * 72 + c) * 2) = f2bf(v); return; }
  else if ((r -= 9216) < 5120)   { src = Wview;
    int n = r / 40, c = r % 40;
    float v = (c < 27) ? src[(long)c * 128 + n] : 0.f;
    *(u16*)(ws + OFF_VIEW + ((long)n * 40 + c) * 2) = f2bf(v); return; }
  else if ((r -= 5120) < 180224) {
    int hi = r / 16384; r %= 16384;
    src = hi == 0 ? Wc : hi <= 4 ? Wb + (long)(hi - 1) * 16384
        : hi == 5 ? Wskipc : hi <= 9 ? Wb + (long)(hi - 2) * 16384 : Wviewc;
    long hbase = HOFF(hi);
    int c = r >> 13;
    int rr = r & 8191;
    int n = rr / 64, k0 = rr % 64;
    float v = src[(long)(64 * c + k0) * 128 + n];
    long boff = (long)n * 128 + ((k0 * 2) ^ ((n & 7) << 4));
    *(u16*)(ws + hbase + (long)c * 16384 + boff) = f2bf(v);
    return;
  }
  r -= 180224;   // 0..383 combined biases
  int which = r >> 7, n = r & 127;
  const float* A  = which == 0 ? bin : (which == 1 ? bskip : bview);
  const float* Bp = which == 0 ? bc  : (which == 1 ? bskipc : bviewc);
  long off = which == 0 ? OFF_B0S : (which == 1 ? OFF_BSK : OFF_BV);
  *(float*)(ws + off + (long)n * 4) = A[n] + Bp[n];
}

// ---------------- staging (256 threads = 4 waves x 1024B = 4096/sweep) ----------------
#define GLL16K(woff)                                                           \
  do {                                                                         \
    _Pragma("unroll") for (int it_ = 0; it_ < 4; ++it_)                        \
      gll16(ws + (woff) + it_ * 4096 + wvu * 1024 + lane * 16,                 \
            lds + LDS_W + it_ * 4096 + wvu * 1024);                            \
  } while (0)

#define GLL_U(woff, nbytes)                                                    \
  do {                                                                         \
    _Pragma("unroll") for (int it_ = 0; it_ < 5; ++it_) {                      \
      int o_ = it_ * 4096 + wvu * 1024;                                        \
      if (o_ < (nbytes))                                                       \
        gll16(ws + (woff) + o_ + lane * 16, lds + LDS_W + o_);                 \
    }                                                                          \
  } while (0)

// 64 rows x 32 f32x4 cols = 2048 / 256 thr = 8 per thread (4-deep batches)
#define STREAM_COND(halfsel)                                                   \
  do {                                                                         \
    _Pragma("unroll") for (int c_ = 0; c_ < 2; ++c_) {                         \
      f32x4 v_[4];                                                             \
      _Pragma("unroll") for (int i2 = 0; i2 < 4; ++i2) {                       \
        int f4i = (4 * c_ + i2) * 256 + tid;                                   \
        int row = f4i >> 5, c4 = f4i & 31;                                     \
        v_[i2] = *(const f32x4*)(condition + (size_t)(p0 + row) * 256 +        \
                                 ((halfsel) * 32 + c4) * 4);                   \
      }                                                                        \
      _Pragma("unroll") for (int i2 = 0; i2 < 4; ++i2) {                       \
        int f4i = (4 * c_ + i2) * 256 + tid;                                   \
        int row = f4i >> 5, c4 = f4i & 31;                                     \
        uint2 t_; t_.x = pack2(v_[i2][0], v_[i2][1]);                          \
        t_.y = pack2(v_[i2][2], v_[i2][3]);                                    \
        *(uint2*)(lds + LDS_X + row * 272 + c4 * 8) = t_;                      \
      }                                                                        \
    }                                                                          \
  } while (0)

#define ENC_LOAD_COMPUTE(EF, LAUNDER)                                          \
  do {                                                                         \
    _Pragma("unroll") for (int mi_ = 0; mi_ < 2; ++mi_) {                      \
      int idx_ = p0 + 32 * wr + 16 * mi_ + li;                                 \
      if (LAUNDER) asm volatile("" : "+v"(idx_));                              \
      const float* cp_ = coords + (size_t)idx_ * 3;                            \
      float c0_ = cp_[0], c1_ = cp_[1], c2_ = cp_[2];                          \
      _Pragma("unroll") for (int kt_ = 0; kt_ < 2; ++kt_) {                    \
        u32 w_[4];                                                             \
        _Pragma("unroll") for (int e2_ = 0; e2_ < 4; ++e2_) {                  \
          int k0_ = kt_ * 32 + h * 8 + e2_ * 2;                                \
          w_[e2_] = pack2(enc_val3(c0_, c1_, c2_, k0_, 63),                    \
                          enc_val3(c0_, c1_, c2_, k0_ + 1, 63));               \
        }                                                                      \
        EF[mi_][kt_] = mk8(w_[0], w_[1], w_[2], w_[3]);                        \
      }                                                                        \
    }                                                                          \
  } while (0)

// ---------------- GEMM pieces: 4 waves, tile M32(wr 0..1) x N64(wc 0..1) ----------------
#define ACC_SET_G(bptr)                                                        \
  do {                                                                         \
    _Pragma("unroll") for (int j = 0; j < 4; ++j) {                            \
      f32x4 b4_ = *(const f32x4*)((bptr) + 64*wc + 16*j + 4*h);                \
      _Pragma("unroll") for (int mi = 0; mi < 2; ++mi) acc[mi][j] = b4_;       \
    }                                                                          \
  } while (0)

#define ACC_ADD_G(bptr)                                                        \
  do {                                                                         \
    _Pragma("unroll") for (int j = 0; j < 4; ++j) {                            \
      f32x4 b4_ = *(const f32x4*)((bptr) + 64*wc + 16*j + 4*h);                \
      _Pragma("unroll") for (int mi = 0; mi < 2; ++mi) acc[mi][j] += b4_;      \
    }                                                                          \
  } while (0)

// swizzled-W GEMM half over K bytes [XO, XO+128) of X
#define GEMM_SWZ(XO)                                                           \
  do {                                                                         \
    int swz_ = (li & 7) << 4;                                                  \
    PRIO(1);                                                                   \
    _Pragma("unroll") for (int kb = 0; kb < 2; ++kb) {                         \
      bf16x8 xf[2];                                                            \
      _Pragma("unroll") for (int mi = 0; mi < 2; ++mi)                         \
        xf[mi] = *(const bf16x8*)(lds + LDS_X + (32*wr + 16*mi + li) * 272 +   \
                                  (XO) + kb * 64 + h16);                       \
      _Pragma("unroll") for (int j = 0; j < 4; ++j) {                          \
        bf16x8 wf = *(const bf16x8*)(lds + LDS_W + (64*wc + 16*j + li) * 128   \
                                     + ((kb * 64 + h16) ^ swz_));              \
        _Pragma("unroll") for (int mi = 0; mi < 2; ++mi)                       \
          acc[mi][j] = MFMA(wf, xf[mi], acc[mi][j], 0, 0, 0);                  \
      }                                                                        \
    }                                                                          \
    PRIO(0);                                                                   \
  } while (0)

#define GEMME01(EF, WSTR)                                                      \
  do {                                                                         \
    PRIO(1);                                                                   \
    _Pragma("unroll") for (int j = 0; j < 4; ++j) {                            \
      const char* wrp = lds + LDS_W + (64*wc + 16*j + li) * (WSTR) + h16;      \
      bf16x8 wf0 = *(const bf16x8*)(wrp);                                      \
      bf16x8 wf1 = *(const bf16x8*)(wrp + 64);                                 \
      _Pragma("unroll") for (int mi = 0; mi < 2; ++mi) {                       \
        acc[mi][j] = MFMA(wf0, EF[mi][0], acc[mi][j], 0, 0, 0);                \
        acc[mi][j] = MFMA(wf1, EF[mi][1], acc[mi][j], 0, 0, 0);                \
      }                                                                        \
    }                                                                          \
    PRIO(0);                                                                   \
  } while (0)

#define STORE_X()                                                              \
  do {                                                                         \
    _Pragma("unroll") for (int mi = 0; mi < 2; ++mi)                           \
    _Pragma("unroll") for (int j = 0; j < 4; ++j) {                            \
      f32x4 v_ = acc[mi][j];                                                   \
      uint2 t_;                                                                \
      t_.x = pack2(fmaxf(v_[0], 0.f), fmaxf(v_[1], 0.f));                      \
      t_.y = pack2(fmaxf(v_[2], 0.f), fmaxf(v_[3], 0.f));                      \
      *(uint2*)(lds + LDS_X + (32*wr + 16*mi + li) * 272 + (64*wc + 16*j + 4*h) * 2) = t_; \
    }                                                                          \
  } while (0)

// heavy phase, single W buffer, plain __syncthreads (TLP across 4 blocks hides)
// entry: chunk0 of heavy HI landed & synced. NOFF<0 -> no next preload.
#define PHASE_HEAVY(BPTR, HI, NOFF, DOSTORE)                                   \
  do {                                                                         \
    if ((const void*)(BPTR) != nullptr) ACC_SET_G((const float*)(BPTR));       \
    GEMM_SWZ(0);                                                               \
    __syncthreads();                                                           \
    GLL16K(HOFF(HI) + 16384);                                                  \
    __syncthreads();                                                           \
    GEMM_SWZ(128);                                                             \
    __syncthreads();                                                           \
    if (DOSTORE) STORE_X();                                                    \
    if ((NOFF) >= 0) GLL16K(HOFF(NOFF));                                       \
    __syncthreads();                                                           \
  } while (0)

// (256,4): 4 blocks/CU (LDS 37888x4 fits), 128-VGPR budget (4 waves/EU) ->
// ample headroom, no spill. 4 independent barrier domains hide staging/barrier
// latency (measured lever: blocks/CU >> intra-block pipelining, R5/R8/R9).
__global__ void __launch_bounds__(256, 4) nerf_main(
    const float* __restrict__ coords, const float* __restrict__ condition,
    const float* __restrict__ ray_dir, const float* __restrict__ noise,
    const float* __restrict__ b_blocks, const float* __restrict__ W_out,
    const float* __restrict__ b_out, const float* __restrict__ W_rgb,
    const float* __restrict__ b_rgb, const char* __restrict__ ws,
    float* __restrict__ out) {
  extern __shared__ __align__(16) char lds[];
  const int tid = threadIdx.x;
  const int lane = tid & 63;
  const int wvu = __builtin_amdgcn_readfirstlane(tid >> 6);  // SGPR wave id 0..3
  const int wr = wvu >> 1, wc = wvu & 1;                     // M32 x N64 tiles
  const int li = lane & 15, h = lane >> 4;
  const int h16 = h * 16;
  const int p0 = blockIdx.x * 64;

  f32x4 acc[2][4];

  // ==== prologue: shape -> X, IN -> W ====
  STREAM_COND(0);
  GLL_U(OFF_IN, 18432);
  __syncthreads();

  // ==== P0: enc@Win (acc = bias0) ====
  {
    bf16x8 encf[2][2];
    ENC_LOAD_COMPUTE(encf, 0);
    ACC_SET_G((const float*)(ws + OFF_B0S));
    GEMME01(encf, 144);
  }
  __syncthreads();
  GLL16K(HOFF(0));
  __syncthreads();

  // ==== RUN1: Wc, Wb0..Wb3 ====
  PHASE_HEAVY(nullptr, 0, 1, 1);                 // Wc (cont), store act0
  PHASE_HEAVY(b_blocks + 0 * 128, 1, 2, 1);      // Wb0
  PHASE_HEAVY(b_blocks + 1 * 128, 2, 3, 1);      // Wb1
  PHASE_HEAVY(b_blocks + 2 * 128, 3, 4, 1);      // Wb2
  PHASE_HEAVY(b_blocks + 3 * 128, 4, -1, 0);     // Wb3 (no store)

  // ==== boundary A: SKIP -> W, X <- shape ====
  GLL_U(OFF_SKIP, 18432);
  STREAM_COND(0);
  __syncthreads();

  // ==== P6: enc@Wskip (cont + biassk) ====
  {
    bf16x8 encf[2][2];
    ENC_LOAD_COMPUTE(encf, 1);
    ACC_ADD_G((const float*)(ws + OFF_BSK));
    GEMME01(encf, 144);
  }
  __syncthreads();
  GLL16K(HOFF(5));
  __syncthreads();

  // ==== RUN2: SKIPC, Wb4..Wb7 ====
  PHASE_HEAVY(nullptr, 5, 6, 1);                 // SKIPC (cont), store act4
  PHASE_HEAVY(b_blocks + 4 * 128, 6, 7, 1);      // Wb4
  PHASE_HEAVY(b_blocks + 5 * 128, 7, 8, 1);      // Wb5
  PHASE_HEAVY(b_blocks + 6 * 128, 8, 9, 1);      // Wb6
  PHASE_HEAVY(b_blocks + 7 * 128, 9, -1, 0);     // Wb7 (no store)

  // ==== boundary B: sigma partials; VIEW -> W; X <- app ====
#pragma unroll
  for (int mi = 0; mi < 2; ++mi) {
    float s = 0.f;
#pragma unroll
    for (int j = 0; j < 4; ++j) {
      f32x4 wo = *(const f32x4*)(W_out + 64 * wc + 16 * j + 4 * h);
#pragma unroll
      for (int rr = 0; rr < 4; ++rr) s += fmaxf(acc[mi][j][rr], 0.f) * wo[rr];
    }
    s += __shfl_xor(s, 16); s += __shfl_xor(s, 32);
    if (h == 0) *(float*)(lds + LDS_SP + ((32 * wr + 16 * mi + li) * 2 + wc) * 4) = s;
  }
  GLL_U(OFF_VIEW, 10240);
  STREAM_COND(1);
  __syncthreads();
  // sigma final: straight to out
  if (tid < 64) {
    const float* sp = (const float*)(lds + LDS_SP);
    float s = sp[2 * tid] + sp[2 * tid + 1] + b_out[0] + noise[p0 + tid];
    out[(size_t)(p0 + tid) * 4] = fmaxf(s, 0.f);
  }

  // ==== P12: enc_v@Wview (cont + biasv) ====
  {
    bf16x8 envf[2];
#pragma unroll
    for (int mi = 0; mi < 2; ++mi) {
      size_t base = (size_t)(p0 + 32 * wr + 16 * mi + li) * 3;
      float r0 = ray_dir[base], r1 = ray_dir[base + 1], r2 = ray_dir[base + 2];
      float inv = 1.f / sqrtf(r0 * r0 + r1 * r1 + r2 * r2);
      r0 *= inv; r1 *= inv; r2 *= inv;
      u32 w[4];
#pragma unroll
      for (int e2 = 0; e2 < 4; ++e2) {
        int k0 = h * 8 + e2 * 2;
        w[e2] = pack2(enc_val3(r0, r1, r2, k0, 27), enc_val3(r0, r1, r2, k0 + 1, 27));
      }
      envf[mi] = mk8(w[0], w[1], w[2], w[3]);
    }
    ACC_ADD_G((const float*)(ws + OFF_BV));
    PRIO(1);
#pragma unroll
    for (int j = 0; j < 4; ++j) {
      bf16x8 wf = *(const bf16x8*)(lds + LDS_W + (64 * wc + 16 * j + li) * 80 + h16);
#pragma unroll
      for (int mi = 0; mi < 2; ++mi)
        acc[mi][j] = MFMA(wf, envf[mi], acc[mi][j], 0, 0, 0);
    }
    PRIO(0);
  }
  __syncthreads();
  GLL16K(HOFF(10));
  __syncthreads();

  // ==== RUN3: VIEWC ====
  PHASE_HEAVY(nullptr, 10, -1, 0);

  // ==== rgb epilogue ====
#pragma unroll
  for (int mi = 0; mi < 2; ++mi) {
    float s0 = 0.f, s1 = 0.f, s2 = 0.f;
#pragma unroll
    for (int j = 0; j < 4; ++j)
#pragma unroll
      for (int rr = 0; rr < 4; ++rr) {
        float v = fmaxf(acc[mi][j][rr], 0.f);
        int n = 64 * wc + 16 * j + 4 * h + rr;
        s0 += v * W_rgb[n * 3 + 0];
        s1 += v * W_rgb[n * 3 + 1];
        s2 += v * W_rgb[n * 3 + 2];
      }
    s0 += __shfl_xor(s0, 16); s0 += __shfl_xor(s0, 32);
    s1 += __shfl_xor(s1, 16); s1 += __shfl_xor(s1, 32);
    s2 += __shfl_xor(s2, 16); s2 += __shfl_xor(s2, 32);
    if (h == 0) {
      float* rp = (float*)(lds + LDS_RP);
      int m_ = 32 * wr + 16 * mi + li;
      rp[(m_ * 2 + wc) * 3 + 0] = s0;
      rp[(m_ * 2 + wc) * 3 + 1] = s1;
      rp[(m_ * 2 + wc) * 3 + 2] = s2;
    }
  }
  __syncthreads();
  if (tid < 64) {
    const float* rp = (const float*)(lds + LDS_RP);
#pragma unroll
    for (int c = 0; c < 3; ++c) {
      float v = rp[(2 * tid) * 3 + c] + rp[(2 * tid + 1) * 3 + c] + b_rgb[c];
      out[(size_t)(p0 + tid) * 4 + 1 + c] = 1.f / (1.f + __expf(-v));
    }
  }
}

extern "C" void kernel_launch(void* const* d_in, const int* in_sizes, int n_in,
                              void* d_out, int out_size, void* d_ws, size_t ws_size,
                              hipStream_t stream) {
  const float* coords    = (const float*)d_in[0];
  const float* condition = (const float*)d_in[1];
  const float* ray_dir   = (const float*)d_in[2];
  const float* noise     = (const float*)d_in[3];
  const float* W_in      = (const float*)d_in[4];
  const float* b_in      = (const float*)d_in[5];
  const float* W_blocks  = (const float*)d_in[6];
  const float* b_blocks  = (const float*)d_in[7];
  const float* W_c       = (const float*)d_in[8];
  const float* b_c       = (const float*)d_in[9];
  const float* W_skip    = (const float*)d_in[10];
  const float* b_skip    = (const float*)d_in[11];
  const float* W_skipc   = (const float*)d_in[12];
  const float* b_skipc   = (const float*)d_in[13];
  const float* W_out     = (const float*)d_in[14];
  const float* b_out     = (const float*)d_in[15];
  const float* W_viewc   = (const float*)d_in[16];
  const float* b_viewc   = (const float*)d_in[17];
  const float* W_view    = (const float*)d_in[18];
  const float* b_view    = (const float*)d_in[19];
  const float* W_rgb     = (const float*)d_in[20];
  const float* b_rgb     = (const float*)d_in[21];
  char* ws = (char*)d_ws;
  float* out = (float*)d_out;

  prep_kernel<<<798, 256, 0, stream>>>(W_in, W_c, W_blocks, W_skip, W_skipc,
                                       W_view, W_viewc, b_in, b_c, b_skip,
                                       b_skipc, b_view, b_viewc, ws);
  nerf_main<<<4096, 256, LDS_TOTAL, stream>>>(coords, condition, ray_dir, noise,
                                              b_blocks, W_out, b_out,
                                              W_rgb, b_rgb, ws, out);
}

// Round 17
// 174.692 us; speedup vs baseline: 1.0797x; 1.0797x over previous
//
#include <hip/hip_runtime.h>
#include <hip/hip_bf16.h>

typedef unsigned int u32;
typedef unsigned short u16;

using bf16x8 = __attribute__((ext_vector_type(8))) short;
using f32x4  = __attribute__((ext_vector_type(4))) float;

// ---------------- workspace layout (bytes), total 407552 ----------------
#define OFF_IN    0L        // [128][72] str144 (k0..62)            18432
#define OFF_SKIP  18432L    // [128][72] str144                      18432
#define OFF_VIEW  36864L    // [128][40] str80  (k0..26)             10240
#define HOFF(i)   (47104L + (long)(i) * 32768L)
// heavy i: chunk0 [128][64] str128 XOR-swz (k0..63) 16384 ; chunk1 same (k64..127) @+16384
// heavy order: 0=Wc 1..4=Wb0..3 5=Wskipc 6..9=Wb4..7 10=Wviewc

// ---------------- LDS layout (bytes) ----------------
#define LDS_X   0        // activations/cond [128][136] bf16 stride 272 = 34816
#define LDS_S0  34816    // weight buffer A (18432)
#define LDS_S1  53248    // weight buffer B (16384, swizzled)
#define LDS_SP  69632    // sigma partials [128][2] f32 = 1024
#define LDS_RP  70656    // rgb partials [128][2][3] f32 = 3072
#define LDS_B   73728    // biases
#define LDS_TOTAL 79360  // x2 blocks/CU (16 waves)
#define BB(i)   (1536 + (i) * 512)

__device__ __forceinline__ u16 f2bf(float x) {
  union { float f; u32 u; } un; un.f = x;
  u32 u = un.u;
  return (u16)((u + 0x7fffu + ((u >> 16) & 1u)) >> 16);
}
__device__ __forceinline__ u32 pack2(float a, float b) {
  u32 r;
  asm("v_cvt_pk_bf16_f32 %0, %1, %2" : "=v"(r) : "v"(a), "v"(b));
  return r;
}
__device__ __forceinline__ float sel3(float a, float b, float c, int i) {
  return i == 0 ? a : (i == 1 ? b : c);
}
__device__ __forceinline__ float enc_val3(float a, float b, float c, int e, int kreal) {
  if (e >= kreal) return 0.f;
  if (e < 3) return sel3(a, b, c, e);
  int t = e - 3;
  int l = t / 6;
  int rem = t - l * 6;
  int pi = rem >= 3 ? rem - 3 : rem;
  float x = sel3(a, b, c, pi) * (float)(1 << l);
  return rem < 3 ? __sinf(x) : __cosf(x);
}
__device__ __forceinline__ bf16x8 mk8(u32 a, u32 b, u32 c, u32 d) {
  union { u32 u[4]; bf16x8 v; } t; t.u[0] = a; t.u[1] = b; t.u[2] = c; t.u[3] = d;
  return t.v;
}
__device__ __forceinline__ void gll16(const void* g, void* l) {
  __builtin_amdgcn_global_load_lds(
      (const __attribute__((address_space(1))) void*)g,
      (__attribute__((address_space(3))) void*)l, 16, 0, 0);
}
#define MFMA __builtin_amdgcn_mfma_f32_16x16x32_bf16
#define SBAR __builtin_amdgcn_s_barrier
#define SCHED0() __builtin_amdgcn_sched_barrier(0)
#define PRIO(n) __builtin_amdgcn_s_setprio(n)

// ---------------- prep ----------------
__global__ void prep_kernel(
    const float* __restrict__ Win, const float* __restrict__ Wc, const float* __restrict__ Wb,
    const float* __restrict__ Wskip, const float* __restrict__ Wskipc,
    const float* __restrict__ Wview, const float* __restrict__ Wviewc,
    char* __restrict__ ws) {
  int i = blockIdx.x * 256 + threadIdx.x;
  if (i >= 203776) return;
  int r = i;
  const float* src;
  if (r < 9216)                  { src = Win;
    int n = r / 72, c = r % 72;
    float v = (c < 63) ? src[(long)c * 128 + n] : 0.f;
    *(u16*)(ws + OFF_IN + ((long)n * 72 + c) * 2) = f2bf(v); return; }
  else if ((r -= 9216) < 9216)   { src = Wskip;
    int n = r / 72, c = r % 72;
    float v = (c < 63) ? src[(long)c * 128 + n] : 0.f;
    *(u16*)(ws + OFF_SKIP + ((long)n * 72 + c) * 2) = f2bf(v); return; }
  else if ((r -= 9216) < 5120)   { src = Wview;
    int n = r / 40, c = r % 40;
    float v = (c < 27) ? src[(long)c * 128 + n] : 0.f;
    *(u16*)(ws + OFF_VIEW + ((long)n * 40 + c) * 2) = f2bf(v); return; }
  r -= 5120;
  int hi = r / 16384; r %= 16384;
  src = hi == 0 ? Wc : hi <= 4 ? Wb + (long)(hi - 1) * 16384
      : hi == 5 ? Wskipc : hi <= 9 ? Wb + (long)(hi - 2) * 16384 : Wviewc;
  long hbase = HOFF(hi);
  int c = r >> 13;
  int rr = r & 8191;
  int n = rr / 64, k0 = rr % 64;
  float v = src[(long)(64 * c + k0) * 128 + n];
  long boff = (long)n * 128 + ((k0 * 2) ^ ((n & 7) << 4));
  *(u16*)(ws + hbase + (long)c * 16384 + boff) = f2bf(v);
}

// ---------------- staging (wvu = SGPR wave id -> SGPR-folded bases) ----------------
#define GLL_H(woff, lbase)                                                     \
  do {                                                                         \
    gll16(ws + (woff) + wvu * 1024 + lane * 16, lds + (lbase) + wvu * 1024);   \
    gll16(ws + (woff) + 8192 + wvu * 1024 + lane * 16,                         \
          lds + (lbase) + 8192 + wvu * 1024);                                  \
  } while (0)

#define GLL_U(woff, lbase, nbytes)                                             \
  do {                                                                         \
    _Pragma("unroll") for (int it_ = 0; it_ < 3; ++it_) {                      \
      int o_ = it_ * 8192 + wvu * 1024;                                        \
      if (o_ < (nbytes))                                                       \
        gll16(ws + (woff) + o_ + lane * 16, lds + (lbase) + o_);               \
    }                                                                          \
  } while (0)

#define STREAM_COND(halfsel)                                                   \
  do {                                                                         \
    _Pragma("unroll") for (int c_ = 0; c_ < 2; ++c_) {                         \
      f32x4 v_[4];                                                             \
      _Pragma("unroll") for (int i2 = 0; i2 < 4; ++i2) {                       \
        int f4i = (4 * c_ + i2) * 512 + tid;                                   \
        int row = f4i >> 5, c4 = f4i & 31;                                     \
        v_[i2] = *(const f32x4*)(condition + (size_t)(p0 + row) * 256 +        \
                                 ((halfsel) * 32 + c4) * 4);                   \
      }                                                                        \
      _Pragma("unroll") for (int i2 = 0; i2 < 4; ++i2) {                       \
        int f4i = (4 * c_ + i2) * 512 + tid;                                   \
        int row = f4i >> 5, c4 = f4i & 31;                                     \
        uint2 t_; t_.x = pack2(v_[i2][0], v_[i2][1]);                          \
        t_.y = pack2(v_[i2][2], v_[i2][3]);                                    \
        *(uint2*)(lds + LDS_X + row * 272 + c4 * 8) = t_;                      \
      }                                                                        \
    }                                                                          \
  } while (0)

#define ENC_LOAD_COMPUTE(EF, LAUNDER)                                          \
  do {                                                                         \
    _Pragma("unroll") for (int mi_ = 0; mi_ < 2; ++mi_) {                      \
      int idx_ = p0 + 32 * wr + 16 * mi_ + li;                                 \
      if (LAUNDER) asm volatile("" : "+v"(idx_));                              \
      const float* cp_ = coords + (size_t)idx_ * 3;                            \
      float c0_ = cp_[0], c1_ = cp_[1], c2_ = cp_[2];                          \
      _Pragma("unroll") for (int kt_ = 0; kt_ < 2; ++kt_) {                    \
        u32 w_[4];                                                             \
        _Pragma("unroll") for (int e2_ = 0; e2_ < 4; ++e2_) {                  \
          int k0_ = kt_ * 32 + h * 8 + e2_ * 2;                                \
          w_[e2_] = pack2(enc_val3(c0_, c1_, c2_, k0_, 63),                    \
                          enc_val3(c0_, c1_, c2_, k0_ + 1, 63));               \
        }                                                                      \
        EF[mi_][kt_] = mk8(w_[0], w_[1], w_[2], w_[3]);                        \
      }                                                                        \
    }                                                                          \
  } while (0)

// ---------------- GEMM pieces: 8 waves, tile M32(wr 0..3) x N64(wc 0..1) ----------------
#define ACC_SET_LDS(BOFF)                                                      \
  do {                                                                         \
    _Pragma("unroll") for (int j = 0; j < 4; ++j) {                            \
      f32x4 b4_ = *(const f32x4*)(lds + LDS_B + (BOFF) + (64*wc + 16*j + 4*h) * 4); \
      _Pragma("unroll") for (int mi = 0; mi < 2; ++mi) acc[mi][j] = b4_;       \
    }                                                                          \
  } while (0)

#define ACC_ADD_LDS(BOFF)                                                      \
  do {                                                                         \
    _Pragma("unroll") for (int j = 0; j < 4; ++j) {                            \
      f32x4 b4_ = *(const f32x4*)(lds + LDS_B + (BOFF) + (64*wc + 16*j + 4*h) * 4); \
      _Pragma("unroll") for (int mi = 0; mi < 2; ++mi) acc[mi][j] += b4_;      \
    }                                                                          \
  } while (0)

#define GEMM_SWZ(SBASE, XO)                                                    \
  do {                                                                         \
    int swz_ = (li & 7) << 4;                                                  \
    PRIO(1);                                                                   \
    _Pragma("unroll") for (int kb = 0; kb < 2; ++kb) {                         \
      bf16x8 xf[2];                                                            \
      _Pragma("unroll") for (int mi = 0; mi < 2; ++mi)                         \
        xf[mi] = *(const bf16x8*)(lds + LDS_X + (32*wr + 16*mi + li) * 272 +   \
                                  (XO) + kb * 64 + h16);                       \
      _Pragma("unroll") for (int j = 0; j < 4; ++j) {                          \
        bf16x8 wf = *(const bf16x8*)(lds + (SBASE) + (64*wc + 16*j + li) * 128 \
                                     + ((kb * 64 + h16) ^ swz_));              \
        _Pragma("unroll") for (int mi = 0; mi < 2; ++mi)                       \
          acc[mi][j] = MFMA(wf, xf[mi], acc[mi][j], 0, 0, 0);                  \
      }                                                                        \
    }                                                                          \
    PRIO(0);                                                                   \
  } while (0)

#define GEMME01(EF)                                                            \
  do {                                                                         \
    PRIO(1);                                                                   \
    _Pragma("unroll") for (int j = 0; j < 4; ++j) {                            \
      const char* wrp = lds + LDS_S0 + (64*wc + 16*j + li) * 144 + h16;        \
      bf16x8 wf0 = *(const bf16x8*)(wrp);                                      \
      bf16x8 wf1 = *(const bf16x8*)(wrp + 64);                                 \
      _Pragma("unroll") for (int mi = 0; mi < 2; ++mi) {                       \
        acc[mi][j] = MFMA(wf0, EF[mi][0], acc[mi][j], 0, 0, 0);                \
        acc[mi][j] = MFMA(wf1, EF[mi][1], acc[mi][j], 0, 0, 0);                \
      }                                                                        \
    }                                                                          \
    PRIO(0);                                                                   \
  } while (0)

#define STORE_X()                                                              \
  do {                                                                         \
    _Pragma("unroll") for (int mi = 0; mi < 2; ++mi)                           \
    _Pragma("unroll") for (int j = 0; j < 4; ++j) {                            \
      f32x4 v_ = acc[mi][j];                                                   \
      uint2 t_;                                                                \
      t_.x = pack2(fmaxf(v_[0], 0.f), fmaxf(v_[1], 0.f));                      \
      t_.y = pack2(fmaxf(v_[2], 0.f), fmaxf(v_[3], 0.f));                      \
      *(uint2*)(lds + LDS_X + (32*wr + 16*mi + li) * 272 + (64*wc + 16*j + 4*h) * 2) = t_; \
    }                                                                          \
  } while (0)

// ---------------- pipelined phases (uniform 2-gll chunks; vmcnt(2) exact) ----------------
#define PHASE_MID(BOFF, NOFF)                                                  \
  do {                                                                         \
    if ((BOFF) >= 0) ACC_SET_LDS(BOFF);                                        \
    GEMM_SWZ(LDS_S0, 0);                                                       \
    SBAR();                                                                    \
    GLL_H((NOFF), LDS_S0);                                                     \
    asm volatile("s_waitcnt vmcnt(2)" ::: "memory");  /* S1(cur) ready */      \
    SCHED0(); SBAR();                                                          \
    GEMM_SWZ(LDS_S1, 128);                                                     \
    SBAR();                                                                    \
    GLL_H((NOFF) + 16384, LDS_S1);                                             \
    asm volatile("s_waitcnt vmcnt(2)" ::: "memory");  /* S0(next) ready */     \
    SCHED0();                                                                  \
    STORE_X();                                                                 \
    asm volatile("s_waitcnt lgkmcnt(0)" ::: "memory");                         \
    SCHED0(); SBAR();                                                          \
  } while (0)

#define PHASE_LAST(BOFF)                                                       \
  do {                                                                         \
    if ((BOFF) >= 0) ACC_SET_LDS(BOFF);                                        \
    GEMM_SWZ(LDS_S0, 0);                                                       \
    asm volatile("s_waitcnt vmcnt(0)" ::: "memory");                           \
    SCHED0(); SBAR();                                                          \
    GEMM_SWZ(LDS_S1, 128);                                                     \
  } while (0)

#define PRELOAD(NOFF)                                                          \
  do {                                                                         \
    GLL_H((NOFF), LDS_S0);                                                     \
    GLL_H((NOFF) + 16384, LDS_S1);                                             \
    asm volatile("s_waitcnt vmcnt(2)" ::: "memory");  /* S0 ready */           \
    SCHED0(); SBAR();                                                          \
  } while (0)

// (512,4): 2 blocks/CU (43% occ), 64-VGPR budget. Wave-uniform values hoisted
// to SGPR via readfirstlane -> spill-free (R15: WRITE_SIZE = output only).
// R16's 4x64-pt-block variant doubled per-point staging and regressed; this
// configuration is the measured optimum of the explored structure space.
__global__ void __launch_bounds__(512, 4) nerf_main(
    const float* __restrict__ coords, const float* __restrict__ condition,
    const float* __restrict__ ray_dir, const float* __restrict__ noise,
    const float* __restrict__ b_in, const float* __restrict__ b_c,
    const float* __restrict__ b_blocks, const float* __restrict__ b_skip,
    const float* __restrict__ b_skipc, const float* __restrict__ b_view,
    const float* __restrict__ b_viewc, const float* __restrict__ W_out,
    const float* __restrict__ b_out, const float* __restrict__ W_rgb,
    const float* __restrict__ b_rgb, const char* __restrict__ ws,
    float* __restrict__ out) {
  extern __shared__ __align__(16) char lds[];
  const int tid = threadIdx.x;
  const int lane = tid & 63;
  const int wvu = __builtin_amdgcn_readfirstlane(tid >> 6);  // SGPR wave id
  const int wr = wvu >> 1, wc = wvu & 1;                     // SGPR tile coords
  const int li = lane & 15, h = lane >> 4;
  const int h16 = h * 16;
  const int p0 = blockIdx.x * 128;

  f32x4 acc[2][4];

  // ==== prologue: biases -> LDS_B, shape -> X, IN -> S0 ====
#pragma unroll
  for (int it = 0; it < 3; ++it) {
    int i = tid + it * 512;
    if (i < 1408) {
      float v = i < 128 ? b_in[i] + b_c[i]
              : i < 256 ? b_skip[i - 128] + b_skipc[i - 128]
              : i < 384 ? b_view[i - 256] + b_viewc[i - 256]
              : b_blocks[i - 384];
      *(float*)(lds + LDS_B + (long)i * 4) = v;
    }
  }
  STREAM_COND(0);
  GLL_U(OFF_IN, LDS_S0, 18432);
  __syncthreads();

  // ==== P0: enc@Win (acc = bias0) ====
  {
    bf16x8 encf[2][2];
    ENC_LOAD_COMPUTE(encf, 0);
    ACC_SET_LDS(0);
    GEMME01(encf);
  }
  __syncthreads();

  // ==== RUN1: Wc, Wb0..Wb3 ====
  PRELOAD(HOFF(0));
  PHASE_MID(-1, HOFF(1));       // Wc (cont), store act0
  PHASE_MID(BB(0), HOFF(2));    // Wb0
  PHASE_MID(BB(1), HOFF(3));    // Wb1
  PHASE_MID(BB(2), HOFF(4));    // Wb2
  PHASE_LAST(BB(3));            // Wb3 (no store; skip adds next)

  // ==== boundary A: SKIP -> S0, X <- shape ====
  GLL_U(OFF_SKIP, LDS_S0, 18432);
  __syncthreads();
  STREAM_COND(0);
  __syncthreads();

  // ==== P6: enc@Wskip (cont + biassk) ====
  {
    bf16x8 encf[2][2];
    ENC_LOAD_COMPUTE(encf, 1);
    ACC_ADD_LDS(512);
    GEMME01(encf);
  }
  __syncthreads();

  // ==== RUN2: SKIPC, Wb4..Wb7 ====
  PRELOAD(HOFF(5));
  PHASE_MID(-1, HOFF(6));       // SKIPC (cont), store act4
  PHASE_MID(BB(4), HOFF(7));    // Wb4
  PHASE_MID(BB(5), HOFF(8));    // Wb5
  PHASE_MID(BB(6), HOFF(9));    // Wb6
  PHASE_LAST(BB(7));            // Wb7 (no store)

  // ==== boundary B: sigma partials; VIEW -> S0; X <- app ====
#pragma unroll
  for (int mi = 0; mi < 2; ++mi) {
    float s = 0.f;
#pragma unroll
    for (int j = 0; j < 4; ++j) {
      f32x4 wo = *(const f32x4*)(W_out + 64 * wc + 16 * j + 4 * h);
#pragma unroll
      for (int rr = 0; rr < 4; ++rr) s += fmaxf(acc[mi][j][rr], 0.f) * wo[rr];
    }
    s += __shfl_xor(s, 16); s += __shfl_xor(s, 32);
    if (h == 0) *(float*)(lds + LDS_SP + ((32 * wr + 16 * mi + li) * 2 + wc) * 4) = s;
  }
  __syncthreads();
  GLL_U(OFF_VIEW, LDS_S0, 10240);
  STREAM_COND(1);
  __syncthreads();
  // sigma final: straight to out
  if (tid < 128) {
    const float* sp = (const float*)(lds + LDS_SP);
    float s = sp[2 * tid] + sp[2 * tid + 1] + b_out[0] + noise[p0 + tid];
    out[(size_t)(p0 + tid) * 4] = fmaxf(s, 0.f);
  }

  // ==== P12: enc_v@Wview (cont + biasv); ray loaded here ====
  {
    bf16x8 envf[2];
#pragma unroll
    for (int mi = 0; mi < 2; ++mi) {
      size_t base = (size_t)(p0 + 32 * wr + 16 * mi + li) * 3;
      float r0 = ray_dir[base], r1 = ray_dir[base + 1], r2 = ray_dir[base + 2];
      float inv = 1.f / sqrtf(r0 * r0 + r1 * r1 + r2 * r2);
      r0 *= inv; r1 *= inv; r2 *= inv;
      u32 w[4];
#pragma unroll
      for (int e2 = 0; e2 < 4; ++e2) {
        int k0 = h * 8 + e2 * 2;
        w[e2] = pack2(enc_val3(r0, r1, r2, k0, 27), enc_val3(r0, r1, r2, k0 + 1, 27));
      }
      envf[mi] = mk8(w[0], w[1], w[2], w[3]);
    }
    ACC_ADD_LDS(1024);
    PRIO(1);
#pragma unroll
    for (int j = 0; j < 4; ++j) {
      bf16x8 wf = *(const bf16x8*)(lds + LDS_S0 + (64 * wc + 16 * j + li) * 80 + h16);
#pragma unroll
      for (int mi = 0; mi < 2; ++mi)
        acc[mi][j] = MFMA(wf, envf[mi], acc[mi][j], 0, 0, 0);
    }
    PRIO(0);
  }
  __syncthreads();

  // ==== RUN3: VIEWC ====
  PRELOAD(HOFF(10));
  PHASE_LAST(-1);

  // ==== rgb epilogue ====
#pragma unroll
  for (int mi = 0; mi < 2; ++mi) {
    float s0 = 0.f, s1 = 0.f, s2 = 0.f;
#pragma unroll
    for (int j = 0; j < 4; ++j)
#pragma unroll
      for (int rr = 0; rr < 4; ++rr) {
        float v = fmaxf(acc[mi][j][rr], 0.f);
        int n = 64 * wc + 16 * j + 4 * h + rr;
        s0 += v * W_rgb[n * 3 + 0];
        s1 += v * W_rgb[n * 3 + 1];
        s2 += v * W_rgb[n * 3 + 2];
      }
    s0 += __shfl_xor(s0, 16); s0 += __shfl_xor(s0, 32);
    s1 += __shfl_xor(s1, 16); s1 += __shfl_xor(s1, 32);
    s2 += __shfl_xor(s2, 16); s2 += __shfl_xor(s2, 32);
    if (h == 0) {
      float* rp = (float*)(lds + LDS_RP);
      int m_ = 32 * wr + 16 * mi + li;
      rp[(m_ * 2 + wc) * 3 + 0] = s0;
      rp[(m_ * 2 + wc) * 3 + 1] = s1;
      rp[(m_ * 2 + wc) * 3 + 2] = s2;
    }
  }
  __syncthreads();
  if (tid < 128) {
    const float* rp = (const float*)(lds + LDS_RP);
#pragma unroll
    for (int c = 0; c < 3; ++c) {
      float v = rp[(2 * tid) * 3 + c] + rp[(2 * tid + 1) * 3 + c] + b_rgb[c];
      out[(size_t)(p0 + tid) * 4 + 1 + c] = 1.f / (1.f + __expf(-v));
    }
  }
}

extern "C" void kernel_launch(void* const* d_in, const int* in_sizes, int n_in,
                              void* d_out, int out_size, void* d_ws, size_t ws_size,
                              hipStream_t stream) {
  const float* coords    = (const float*)d_in[0];
  const float* condition = (const float*)d_in[1];
  const float* ray_dir   = (const float*)d_in[2];
  const float* noise     = (const float*)d_in[3];
  const float* W_in      = (const float*)d_in[4];
  const float* b_in      = (const float*)d_in[5];
  const float* W_blocks  = (const float*)d_in[6];
  const float* b_blocks  = (const float*)d_in[7];
  const float* W_c       = (const float*)d_in[8];
  const float* b_c       = (const float*)d_in[9];
  const float* W_skip    = (const float*)d_in[10];
  const float* b_skip    = (const float*)d_in[11];
  const float* W_skipc   = (const float*)d_in[12];
  const float* b_skipc   = (const float*)d_in[13];
  const float* W_out     = (const float*)d_in[14];
  const float* b_out     = (const float*)d_in[15];
  const float* W_viewc   = (const float*)d_in[16];
  const float* b_viewc   = (const float*)d_in[17];
  const float* W_view    = (const float*)d_in[18];
  const float* b_view    = (const float*)d_in[19];
  const float* W_rgb     = (const float*)d_in[20];
  const float* b_rgb     = (const float*)d_in[21];
  char* ws = (char*)d_ws;
  float* out = (float*)d_out;

  prep_kernel<<<796, 256, 0, stream>>>(W_in, W_c, W_blocks, W_skip, W_skipc,
                                       W_view, W_viewc, ws);
  nerf_main<<<2048, 512, LDS_TOTAL, stream>>>(coords, condition, ray_dir, noise,
                                              b_in, b_c, b_blocks, b_skip, b_skipc,
                                              b_view, b_viewc, W_out, b_out,
                                              W_rgb, b_rgb, ws, out);
}

// Round 18
// 172.841 us; speedup vs baseline: 1.0913x; 1.0107x over previous
//
#include <hip/hip_runtime.h>
#include <hip/hip_bf16.h>

typedef unsigned int u32;
typedef unsigned short u16;

using bf16x8 = __attribute__((ext_vector_type(8))) short;
using f32x4  = __attribute__((ext_vector_type(4))) float;

// ---------------- workspace layout (bytes), total 407552 ----------------
#define OFF_IN    0L        // [128][72] str144 (k0..62)            18432
#define OFF_SKIP  18432L    // [128][72] str144                      18432
#define OFF_VIEW  36864L    // [128][40] str80  (k0..26)             10240
#define HOFF(i)   (47104L + (long)(i) * 32768L)
// heavy i: chunk0 [128][64] str128 XOR-swz (k0..63) 16384 ; chunk1 same (k64..127) @+16384
// heavy order: 0=Wc 1..4=Wb0..3 5=Wskipc 6..9=Wb4..7 10=Wviewc

// ---------------- LDS layout (bytes) ----------------
// X stride 264 (66 words = 2 mod 32): xf start bank = (2*li+4*h)%32 -> 4-way
// aliasing (1.58x) vs 272's 8-way (2.94x, m136). 264 holds 128 bf16 + 8B pad.
#define XSTR    264
#define LDS_X   0        // activations/cond [128][264B] = 33792
#define LDS_S0  33792    // weight buffer A (18432)
#define LDS_S1  52224    // weight buffer B (16384, swizzled)
#define LDS_SP  68608    // sigma partials [128][2] f32 = 1024
#define LDS_RP  69632    // rgb partials [128][2][3] f32 = 3072
#define LDS_B   72704    // biases (5632)
#define LDS_TOTAL 78336  // x2 blocks/CU (16 waves)
#define BB(i)   (1536 + (i) * 512)

__device__ __forceinline__ u16 f2bf(float x) {
  union { float f; u32 u; } un; un.f = x;
  u32 u = un.u;
  return (u16)((u + 0x7fffu + ((u >> 16) & 1u)) >> 16);
}
__device__ __forceinline__ u32 pack2(float a, float b) {
  u32 r;
  asm("v_cvt_pk_bf16_f32 %0, %1, %2" : "=v"(r) : "v"(a), "v"(b));
  return r;
}
__device__ __forceinline__ float sel3(float a, float b, float c, int i) {
  return i == 0 ? a : (i == 1 ? b : c);
}
__device__ __forceinline__ float enc_val3(float a, float b, float c, int e, int kreal) {
  if (e >= kreal) return 0.f;
  if (e < 3) return sel3(a, b, c, e);
  int t = e - 3;
  int l = t / 6;
  int rem = t - l * 6;
  int pi = rem >= 3 ? rem - 3 : rem;
  float x = sel3(a, b, c, pi) * (float)(1 << l);
  return rem < 3 ? __sinf(x) : __cosf(x);
}
__device__ __forceinline__ bf16x8 mk8(u32 a, u32 b, u32 c, u32 d) {
  union { u32 u[4]; bf16x8 v; } t; t.u[0] = a; t.u[1] = b; t.u[2] = c; t.u[3] = d;
  return t.v;
}
__device__ __forceinline__ void gll16(const void* g, void* l) {
  __builtin_amdgcn_global_load_lds(
      (const __attribute__((address_space(1))) void*)g,
      (__attribute__((address_space(3))) void*)l, 16, 0, 0);
}
#define MFMA __builtin_amdgcn_mfma_f32_16x16x32_bf16
#define SBAR __builtin_amdgcn_s_barrier
#define SCHED0() __builtin_amdgcn_sched_barrier(0)
#define PRIO(n) __builtin_amdgcn_s_setprio(n)

// ---------------- prep (unchanged) ----------------
__global__ void prep_kernel(
    const float* __restrict__ Win, const float* __restrict__ Wc, const float* __restrict__ Wb,
    const float* __restrict__ Wskip, const float* __restrict__ Wskipc,
    const float* __restrict__ Wview, const float* __restrict__ Wviewc,
    char* __restrict__ ws) {
  int i = blockIdx.x * 256 + threadIdx.x;
  if (i >= 203776) return;
  int r = i;
  const float* src;
  if (r < 9216)                  { src = Win;
    int n = r / 72, c = r % 72;
    float v = (c < 63) ? src[(long)c * 128 + n] : 0.f;
    *(u16*)(ws + OFF_IN + ((long)n * 72 + c) * 2) = f2bf(v); return; }
  else if ((r -= 9216) < 9216)   { src = Wskip;
    int n = r / 72, c = r % 72;
    float v = (c < 63) ? src[(long)c * 128 + n] : 0.f;
    *(u16*)(ws + OFF_SKIP + ((long)n * 72 + c) * 2) = f2bf(v); return; }
  else if ((r -= 9216) < 5120)   { src = Wview;
    int n = r / 40, c = r % 40;
    float v = (c < 27) ? src[(long)c * 128 + n] : 0.f;
    *(u16*)(ws + OFF_VIEW + ((long)n * 40 + c) * 2) = f2bf(v); return; }
  r -= 5120;
  int hi = r / 16384; r %= 16384;
  src = hi == 0 ? Wc : hi <= 4 ? Wb + (long)(hi - 1) * 16384
      : hi == 5 ? Wskipc : hi <= 9 ? Wb + (long)(hi - 2) * 16384 : Wviewc;
  long hbase = HOFF(hi);
  int c = r >> 13;
  int rr = r & 8191;
  int n = rr / 64, k0 = rr % 64;
  float v = src[(long)(64 * c + k0) * 128 + n];
  long boff = (long)n * 128 + ((k0 * 2) ^ ((n & 7) << 4));
  *(u16*)(ws + hbase + (long)c * 16384 + boff) = f2bf(v);
}

// ---------------- staging (wvu = SGPR wave id -> SGPR-folded bases) ----------------
#define GLL_H(woff, lbase)                                                     \
  do {                                                                         \
    gll16(ws + (woff) + wvu * 1024 + lane * 16, lds + (lbase) + wvu * 1024);   \
    gll16(ws + (woff) + 8192 + wvu * 1024 + lane * 16,                         \
          lds + (lbase) + 8192 + wvu * 1024);                                  \
  } while (0)

#define GLL_U(woff, lbase, nbytes)                                             \
  do {                                                                         \
    _Pragma("unroll") for (int it_ = 0; it_ < 3; ++it_) {                      \
      int o_ = it_ * 8192 + wvu * 1024;                                        \
      if (o_ < (nbytes))                                                       \
        gll16(ws + (woff) + o_ + lane * 16, lds + (lbase) + o_);               \
    }                                                                          \
  } while (0)

#define STREAM_COND(halfsel)                                                   \
  do {                                                                         \
    _Pragma("unroll") for (int c_ = 0; c_ < 2; ++c_) {                         \
      f32x4 v_[4];                                                             \
      _Pragma("unroll") for (int i2 = 0; i2 < 4; ++i2) {                       \
        int f4i = (4 * c_ + i2) * 512 + tid;                                   \
        int row = f4i >> 5, c4 = f4i & 31;                                     \
        v_[i2] = *(const f32x4*)(condition + (size_t)(p0 + row) * 256 +        \
                                 ((halfsel) * 32 + c4) * 4);                   \
      }                                                                        \
      _Pragma("unroll") for (int i2 = 0; i2 < 4; ++i2) {                       \
        int f4i = (4 * c_ + i2) * 512 + tid;                                   \
        int row = f4i >> 5, c4 = f4i & 31;                                     \
        uint2 t_; t_.x = pack2(v_[i2][0], v_[i2][1]);                          \
        t_.y = pack2(v_[i2][2], v_[i2][3]);                                    \
        *(uint2*)(lds + LDS_X + row * XSTR + c4 * 8) = t_;                     \
      }                                                                        \
    }                                                                          \
  } while (0)

#define ENC_LOAD_COMPUTE(EF, LAUNDER)                                          \
  do {                                                                         \
    _Pragma("unroll") for (int mi_ = 0; mi_ < 2; ++mi_) {                      \
      int idx_ = p0 + 32 * wr + 16 * mi_ + li;                                 \
      if (LAUNDER) asm volatile("" : "+v"(idx_));                              \
      const float* cp_ = coords + (size_t)idx_ * 3;                            \
      float c0_ = cp_[0], c1_ = cp_[1], c2_ = cp_[2];                          \
      _Pragma("unroll") for (int kt_ = 0; kt_ < 2; ++kt_) {                    \
        u32 w_[4];                                                             \
        _Pragma("unroll") for (int e2_ = 0; e2_ < 4; ++e2_) {                  \
          int k0_ = kt_ * 32 + h * 8 + e2_ * 2;                                \
          w_[e2_] = pack2(enc_val3(c0_, c1_, c2_, k0_, 63),                    \
                          enc_val3(c0_, c1_, c2_, k0_ + 1, 63));               \
        }                                                                      \
        EF[mi_][kt_] = mk8(w_[0], w_[1], w_[2], w_[3]);                        \
      }                                                                        \
    }                                                                          \
  } while (0)

// ---------------- GEMM pieces: 8 waves, tile M32(wr 0..3) x N64(wc 0..1) ----------------
#define ACC_SET_LDS(BOFF)                                                      \
  do {                                                                         \
    _Pragma("unroll") for (int j = 0; j < 4; ++j) {                            \
      f32x4 b4_ = *(const f32x4*)(lds + LDS_B + (BOFF) + (64*wc + 16*j + 4*h) * 4); \
      _Pragma("unroll") for (int mi = 0; mi < 2; ++mi) acc[mi][j] = b4_;       \
    }                                                                          \
  } while (0)

#define ACC_ADD_LDS(BOFF)                                                      \
  do {                                                                         \
    _Pragma("unroll") for (int j = 0; j < 4; ++j) {                            \
      f32x4 b4_ = *(const f32x4*)(lds + LDS_B + (BOFF) + (64*wc + 16*j + 4*h) * 4); \
      _Pragma("unroll") for (int mi = 0; mi < 2; ++mi) acc[mi][j] += b4_;      \
    }                                                                          \
  } while (0)

#define GEMM_SWZ(SBASE, XO)                                                    \
  do {                                                                         \
    int swz_ = (li & 7) << 4;                                                  \
    PRIO(1);                                                                   \
    _Pragma("unroll") for (int kb = 0; kb < 2; ++kb) {                         \
      bf16x8 xf[2];                                                            \
      _Pragma("unroll") for (int mi = 0; mi < 2; ++mi)                         \
        xf[mi] = *(const bf16x8*)(lds + LDS_X + (32*wr + 16*mi + li) * XSTR +  \
                                  (XO) + kb * 64 + h16);                       \
      _Pragma("unroll") for (int j = 0; j < 4; ++j) {                          \
        bf16x8 wf = *(const bf16x8*)(lds + (SBASE) + (64*wc + 16*j + li) * 128 \
                                     + ((kb * 64 + h16) ^ swz_));              \
        _Pragma("unroll") for (int mi = 0; mi < 2; ++mi)                       \
          acc[mi][j] = MFMA(wf, xf[mi], acc[mi][j], 0, 0, 0);                  \
      }                                                                        \
    }                                                                          \
    PRIO(0);                                                                   \
  } while (0)

#define GEMME01(EF)                                                            \
  do {                                                                         \
    PRIO(1);                                                                   \
    _Pragma("unroll") for (int j = 0; j < 4; ++j) {                            \
      const char* wrp = lds + LDS_S0 + (64*wc + 16*j + li) * 144 + h16;        \
      bf16x8 wf0 = *(const bf16x8*)(wrp);                                      \
      bf16x8 wf1 = *(const bf16x8*)(wrp + 64);                                 \
      _Pragma("unroll") for (int mi = 0; mi < 2; ++mi) {                       \
        acc[mi][j] = MFMA(wf0, EF[mi][0], acc[mi][j], 0, 0, 0);                \
        acc[mi][j] = MFMA(wf1, EF[mi][1], acc[mi][j], 0, 0, 0);                \
      }                                                                        \
    }                                                                          \
    PRIO(0);                                                                   \
  } while (0)

#define STORE_X()                                                              \
  do {                                                                         \
    _Pragma("unroll") for (int mi = 0; mi < 2; ++mi)                           \
    _Pragma("unroll") for (int j = 0; j < 4; ++j) {                            \
      f32x4 v_ = acc[mi][j];                                                   \
      uint2 t_;                                                                \
      t_.x = pack2(fmaxf(v_[0], 0.f), fmaxf(v_[1], 0.f));                      \
      t_.y = pack2(fmaxf(v_[2], 0.f), fmaxf(v_[3], 0.f));                      \
      *(uint2*)(lds + LDS_X + (32*wr + 16*mi + li) * XSTR + (64*wc + 16*j + 4*h) * 2) = t_; \
    }                                                                          \
  } while (0)

// ---------------- pipelined phases (uniform 2-gll chunks; vmcnt(2) exact) ----------------
#define PHASE_MID(BOFF, NOFF)                                                  \
  do {                                                                         \
    if ((BOFF) >= 0) ACC_SET_LDS(BOFF);                                        \
    GEMM_SWZ(LDS_S0, 0);                                                       \
    SBAR();                                                                    \
    GLL_H((NOFF), LDS_S0);                                                     \
    asm volatile("s_waitcnt vmcnt(2)" ::: "memory");  /* S1(cur) ready */      \
    SCHED0(); SBAR();                                                          \
    GEMM_SWZ(LDS_S1, 128);                                                     \
    SBAR();                                                                    \
    GLL_H((NOFF) + 16384, LDS_S1);                                             \
    asm volatile("s_waitcnt vmcnt(2)" ::: "memory");  /* S0(next) ready */     \
    SCHED0();                                                                  \
    STORE_X();                                                                 \
    asm volatile("s_waitcnt lgkmcnt(0)" ::: "memory");                         \
    SCHED0(); SBAR();                                                          \
  } while (0)

#define PHASE_LAST(BOFF)                                                       \
  do {                                                                         \
    if ((BOFF) >= 0) ACC_SET_LDS(BOFF);                                        \
    GEMM_SWZ(LDS_S0, 0);                                                       \
    asm volatile("s_waitcnt vmcnt(0)" ::: "memory");                           \
    SCHED0(); SBAR();                                                          \
    GEMM_SWZ(LDS_S1, 128);                                                     \
  } while (0)

#define PRELOAD(NOFF)                                                          \
  do {                                                                         \
    GLL_H((NOFF), LDS_S0);                                                     \
    GLL_H((NOFF) + 16384, LDS_S1);                                             \
    asm volatile("s_waitcnt vmcnt(2)" ::: "memory");  /* S0 ready */           \
    SCHED0(); SBAR();                                                          \
  } while (0)

// (512,4): 2 blocks/CU, 64-VGPR budget, SGPR-hoisted bases (spill-free).
// This round: X stride 272 -> 264 to cut xf-read bank conflicts 8-way -> 4-way.
__global__ void __launch_bounds__(512, 4) nerf_main(
    const float* __restrict__ coords, const float* __restrict__ condition,
    const float* __restrict__ ray_dir, const float* __restrict__ noise,
    const float* __restrict__ b_in, const float* __restrict__ b_c,
    const float* __restrict__ b_blocks, const float* __restrict__ b_skip,
    const float* __restrict__ b_skipc, const float* __restrict__ b_view,
    const float* __restrict__ b_viewc, const float* __restrict__ W_out,
    const float* __restrict__ b_out, const float* __restrict__ W_rgb,
    const float* __restrict__ b_rgb, const char* __restrict__ ws,
    float* __restrict__ out) {
  extern __shared__ __align__(16) char lds[];
  const int tid = threadIdx.x;
  const int lane = tid & 63;
  const int wvu = __builtin_amdgcn_readfirstlane(tid >> 6);  // SGPR wave id
  const int wr = wvu >> 1, wc = wvu & 1;                     // SGPR tile coords
  const int li = lane & 15, h = lane >> 4;
  const int h16 = h * 16;
  const int p0 = blockIdx.x * 128;

  f32x4 acc[2][4];

  // ==== prologue: biases -> LDS_B, shape -> X, IN -> S0 ====
#pragma unroll
  for (int it = 0; it < 3; ++it) {
    int i = tid + it * 512;
    if (i < 1408) {
      float v = i < 128 ? b_in[i] + b_c[i]
              : i < 256 ? b_skip[i - 128] + b_skipc[i - 128]
              : i < 384 ? b_view[i - 256] + b_viewc[i - 256]
              : b_blocks[i - 384];
      *(float*)(lds + LDS_B + (long)i * 4) = v;
    }
  }
  STREAM_COND(0);
  GLL_U(OFF_IN, LDS_S0, 18432);
  __syncthreads();

  // ==== P0: enc@Win (acc = bias0) ====
  {
    bf16x8 encf[2][2];
    ENC_LOAD_COMPUTE(encf, 0);
    ACC_SET_LDS(0);
    GEMME01(encf);
  }
  __syncthreads();

  // ==== RUN1: Wc, Wb0..Wb3 ====
  PRELOAD(HOFF(0));
  PHASE_MID(-1, HOFF(1));       // Wc (cont), store act0
  PHASE_MID(BB(0), HOFF(2));    // Wb0
  PHASE_MID(BB(1), HOFF(3));    // Wb1
  PHASE_MID(BB(2), HOFF(4));    // Wb2
  PHASE_LAST(BB(3));            // Wb3 (no store; skip adds next)

  // ==== boundary A: SKIP -> S0, X <- shape ====
  GLL_U(OFF_SKIP, LDS_S0, 18432);
  __syncthreads();
  STREAM_COND(0);
  __syncthreads();

  // ==== P6: enc@Wskip (cont + biassk) ====
  {
    bf16x8 encf[2][2];
    ENC_LOAD_COMPUTE(encf, 1);
    ACC_ADD_LDS(512);
    GEMME01(encf);
  }
  __syncthreads();

  // ==== RUN2: SKIPC, Wb4..Wb7 ====
  PRELOAD(HOFF(5));
  PHASE_MID(-1, HOFF(6));       // SKIPC (cont), store act4
  PHASE_MID(BB(4), HOFF(7));    // Wb4
  PHASE_MID(BB(5), HOFF(8));    // Wb5
  PHASE_MID(BB(6), HOFF(9));    // Wb6
  PHASE_LAST(BB(7));            // Wb7 (no store)

  // ==== boundary B: sigma partials; VIEW -> S0; X <- app ====
#pragma unroll
  for (int mi = 0; mi < 2; ++mi) {
    float s = 0.f;
#pragma unroll
    for (int j = 0; j < 4; ++j) {
      f32x4 wo = *(const f32x4*)(W_out + 64 * wc + 16 * j + 4 * h);
#pragma unroll
      for (int rr = 0; rr < 4; ++rr) s += fmaxf(acc[mi][j][rr], 0.f) * wo[rr];
    }
    s += __shfl_xor(s, 16); s += __shfl_xor(s, 32);
    if (h == 0) *(float*)(lds + LDS_SP + ((32 * wr + 16 * mi + li) * 2 + wc) * 4) = s;
  }
  __syncthreads();
  GLL_U(OFF_VIEW, LDS_S0, 10240);
  STREAM_COND(1);
  __syncthreads();
  // sigma final: straight to out
  if (tid < 128) {
    const float* sp = (const float*)(lds + LDS_SP);
    float s = sp[2 * tid] + sp[2 * tid + 1] + b_out[0] + noise[p0 + tid];
    out[(size_t)(p0 + tid) * 4] = fmaxf(s, 0.f);
  }

  // ==== P12: enc_v@Wview (cont + biasv); ray loaded here ====
  {
    bf16x8 envf[2];
#pragma unroll
    for (int mi = 0; mi < 2; ++mi) {
      size_t base = (size_t)(p0 + 32 * wr + 16 * mi + li) * 3;
      float r0 = ray_dir[base], r1 = ray_dir[base + 1], r2 = ray_dir[base + 2];
      float inv = 1.f / sqrtf(r0 * r0 + r1 * r1 + r2 * r2);
      r0 *= inv; r1 *= inv; r2 *= inv;
      u32 w[4];
#pragma unroll
      for (int e2 = 0; e2 < 4; ++e2) {
        int k0 = h * 8 + e2 * 2;
        w[e2] = pack2(enc_val3(r0, r1, r2, k0, 27), enc_val3(r0, r1, r2, k0 + 1, 27));
      }
      envf[mi] = mk8(w[0], w[1], w[2], w[3]);
    }
    ACC_ADD_LDS(1024);
    PRIO(1);
#pragma unroll
    for (int j = 0; j < 4; ++j) {
      bf16x8 wf = *(const bf16x8*)(lds + LDS_S0 + (64 * wc + 16 * j + li) * 80 + h16);
#pragma unroll
      for (int mi = 0; mi < 2; ++mi)
        acc[mi][j] = MFMA(wf, envf[mi], acc[mi][j], 0, 0, 0);
    }
    PRIO(0);
  }
  __syncthreads();

  // ==== RUN3: VIEWC ====
  PRELOAD(HOFF(10));
  PHASE_LAST(-1);

  // ==== rgb epilogue ====
#pragma unroll
  for (int mi = 0; mi < 2; ++mi) {
    float s0 = 0.f, s1 = 0.f, s2 = 0.f;
#pragma unroll
    for (int j = 0; j < 4; ++j)
#pragma unroll
      for (int rr = 0; rr < 4; ++rr) {
        float v = fmaxf(acc[mi][j][rr], 0.f);
        int n = 64 * wc + 16 * j + 4 * h + rr;
        s0 += v * W_rgb[n * 3 + 0];
        s1 += v * W_rgb[n * 3 + 1];
        s2 += v * W_rgb[n * 3 + 2];
      }
    s0 += __shfl_xor(s0, 16); s0 += __shfl_xor(s0, 32);
    s1 += __shfl_xor(s1, 16); s1 += __shfl_xor(s1, 32);
    s2 += __shfl_xor(s2, 16); s2 += __shfl_xor(s2, 32);
    if (h == 0) {
      float* rp = (float*)(lds + LDS_RP);
      int m_ = 32 * wr + 16 * mi + li;
      rp[(m_ * 2 + wc) * 3 + 0] = s0;
      rp[(m_ * 2 + wc) * 3 + 1] = s1;
      rp[(m_ * 2 + wc) * 3 + 2] = s2;
    }
  }
  __syncthreads();
  if (tid < 128) {
    const float* rp = (const float*)(lds + LDS_RP);
#pragma unroll
    for (int c = 0; c < 3; ++c) {
      float v = rp[(2 * tid) * 3 + c] + rp[(2 * tid + 1) * 3 + c] + b_rgb[c];
      out[(size_t)(p0 + tid) * 4 + 1 + c] = 1.f / (1.f + __expf(-v));
    }
  }
}

extern "C" void kernel_launch(void* const* d_in, const int* in_sizes, int n_in,
                              void* d_out, int out_size, void* d_ws, size_t ws_size,
                              hipStream_t stream) {
  const float* coords    = (const float*)d_in[0];
  const float* condition = (const float*)d_in[1];
  const float* ray_dir   = (const float*)d_in[2];
  const float* noise     = (const float*)d_in[3];
  const float* W_in      = (const float*)d_in[4];
  const float* b_in      = (const float*)d_in[5];
  const float* W_blocks  = (const float*)d_in[6];
  const float* b_blocks  = (const float*)d_in[7];
  const float* W_c       = (const float*)d_in[8];
  const float* b_c       = (const float*)d_in[9];
  const float* W_skip    = (const float*)d_in[10];
  const float* b_skip    = (const float*)d_in[11];
  const float* W_skipc   = (const float*)d_in[12];
  const float* b_skipc   = (const float*)d_in[13];
  const float* W_out     = (const float*)d_in[14];
  const float* b_out     = (const float*)d_in[15];
  const float* W_viewc   = (const float*)d_in[16];
  const float* b_viewc   = (const float*)d_in[17];
  const float* W_view    = (const float*)d_in[18];
  const float* b_view    = (const float*)d_in[19];
  const float* W_rgb     = (const float*)d_in[20];
  const float* b_rgb     = (const float*)d_in[21];
  char* ws = (char*)d_ws;
  float* out = (float*)d_out;

  prep_kernel<<<796, 256, 0, stream>>>(W_in, W_c, W_blocks, W_skip, W_skipc,
                                       W_view, W_viewc, ws);
  nerf_main<<<2048, 512, LDS_TOTAL, stream>>>(coords, condition, ray_dir, noise,
                                              b_in, b_c, b_blocks, b_skip, b_skipc,
                                              b_view, b_viewc, W_out, b_out,
                                              W_rgb, b_rgb, ws, out);
}